// Round 5
// baseline (225.080 us; speedup 1.0000x reference)
//
#include <hip/hip_runtime.h>

// Problem: x[T][E] f32, W[E][O] f32, bias[O] f32, lengths[B] int32.
// out[B][O] = (segment_mean(x, lengths) @ W) + bias
// T=131072, E=2048, O=1024, B=16 (derived at launch from in_sizes).
//
// Roofline: one streaming read of x (1.074 GB) => ~172 us at 6.3 TB/s.
//
// Phase 1 (seg_partial): GLOBAL 64-row chunks, exactly T/64 = 2048 blocks =
//   256 CU x 8 blocks/CU. FAST PATH (~2033 blocks): chunk entirely inside one
//   segment -> compile-time 64-trip loop, unroll 4, 8 nt-loads in flight/wave
//   (R4 lesson: runtime-bounded loop inside a while broke unrolling, -6%).
//   SLOW PATH (<=15 blocks): per-segment split, first part -> main[g],
//   later parts -> extra[b].
// Phase 2 (reduce_p2): 16-way split deterministic reduction -> p2[b][s][e].
// Phase 3 (gemm_out): 4 segments/block, folds 16-way sum + 1/len into LDS
//   staging, W element reused 4x.

#define E_DIM 2048
#define O_DIM 1024
#define RCH 64        // rows per global chunk
#define S_SPLIT 16    // phase-2 split factor
#define B_TILE 4      // segments per gemm block

typedef float v4f __attribute__((ext_vector_type(4)));

// ---------------------------------------------------------------------------
__global__ __launch_bounds__(256, 8) void seg_partial(const float* __restrict__ x,
                                                      const int* __restrict__ lengths,
                                                      int Bn, int Tn,
                                                      float* __restrict__ mainp,
                                                      float* __restrict__ extrap) {
    const int g  = blockIdx.x;
    const int r0 = g * RCH;
    const int rEnd = min(r0 + RCH, Tn);

    // owner segment of row r0 (lengths: 16 ints, L1-hot; uniform branch)
    int b = 0, segEnd = lengths[0];
    while (segEnd <= r0) { ++b; segEnd += lengths[b]; }

    const int tx = threadIdx.x;
    const v4f* p = (const v4f*)(x + (size_t)r0 * E_DIM + tx * 4);

    if (segEnd >= rEnd && rEnd == r0 + RCH) {
        // ---- fast path: whole chunk in one segment, compile-time trip count
        v4f a0 = {0.f, 0.f, 0.f, 0.f};
        v4f a1 = {0.f, 0.f, 0.f, 0.f};
#pragma unroll 4
        for (int r = 0; r < RCH; ++r) {
            v4f v0 = __builtin_nontemporal_load(p);        // x read exactly once
            v4f v1 = __builtin_nontemporal_load(p + 256);  // +1024 floats
            a0 += v0;
            a1 += v1;
            p += E_DIM / 4;
        }
        v4f* d = (v4f*)(mainp + (size_t)g * E_DIM) + tx;
        d[0]   = a0;
        d[256] = a1;
        return;
    }

    // ---- slow path: chunk crosses >=1 segment boundary (<=15 blocks)
    v4f a0 = {0.f, 0.f, 0.f, 0.f};
    v4f a1 = {0.f, 0.f, 0.f, 0.f};
    int r = r0;
    bool first = true;
    while (true) {
        const int stop = min(rEnd, segEnd);
        for (; r < stop; ++r) {
            v4f v0 = __builtin_nontemporal_load(p);
            v4f v1 = __builtin_nontemporal_load(p + 256);
            a0 += v0;
            a1 += v1;
            p += E_DIM / 4;
        }
        float* dst = first ? (mainp + (size_t)g * E_DIM)
                           : (extrap + (size_t)b * E_DIM);
        v4f* d = (v4f*)dst + tx;
        d[0]   = a0;
        d[256] = a1;
        if (r >= rEnd) break;
        first = false;
        ++b; segEnd += lengths[b];
        a0 = (v4f){0.f, 0.f, 0.f, 0.f};
        a1 = (v4f){0.f, 0.f, 0.f, 0.f};
    }
}

// ---------------------------------------------------------------------------
// Segment b's main chunks are g in [ceil(start/64), floor((end-1)/64)]
// (empty when the segment lives inside a chunk it doesn't own); plus
// extra[b] iff start % 64 != 0. Fixed order => deterministic.
// grid = (E/1024, B, S_SPLIT), block = 256.
// ---------------------------------------------------------------------------
__global__ __launch_bounds__(256) void reduce_p2(const float* __restrict__ mainp,
                                                 const float* __restrict__ extrap,
                                                 const int* __restrict__ lengths,
                                                 float* __restrict__ p2) {
    const int b = blockIdx.y;
    const int s = blockIdx.z;
    int start = 0;
    for (int i = 0; i < b; ++i) start += lengths[i];
    const int end = start + lengths[b];
    const int g0 = (start + RCH - 1) / RCH;
    const int g1 = (end - 1) / RCH;                 // inclusive
    const int nch = (g1 >= g0) ? (g1 - g0 + 1) : 0;
    const int c0 = g0 + (nch * s) / S_SPLIT;
    const int c1 = g0 + (nch * (s + 1)) / S_SPLIT;

    const int col = blockIdx.x * 1024 + threadIdx.x * 4;
    v4f acc = {0.f, 0.f, 0.f, 0.f};
    const v4f* p = (const v4f*)(mainp + (size_t)c0 * E_DIM + col);
#pragma unroll 8
    for (int c = c0; c < c1; ++c) {                 // fixed order: deterministic
        acc += *p;
        p += E_DIM / 4;
    }
    if (s == 0 && (start % RCH) != 0)
        acc += *(const v4f*)(extrap + (size_t)b * E_DIM + col);
    *(v4f*)(p2 + ((size_t)(b * S_SPLIT + s)) * E_DIM + col) = acc;
}

// ---------------------------------------------------------------------------
// out[b][o] = dot(mean[b][:], W[:][o]) + bias[o]
// grid = (O/64, B/B_TILE) = 64 blocks; block = 512 = 64 outputs x 8 e-groups.
// Each W element loaded once serves B_TILE segments (4 indep accumulators).
// ---------------------------------------------------------------------------
__global__ __launch_bounds__(512) void gemm_out(const float* __restrict__ p2,
                                                const float* __restrict__ W,
                                                const float* __restrict__ bias,
                                                const int* __restrict__ lengths,
                                                float* __restrict__ out) {
    const int oc = blockIdx.x;
    const int bc = blockIdx.y;
    const int tx = threadIdx.x;
    const int olocal = tx & 63;
    const int eg     = tx >> 6;                    // 8 e-groups of 256
    const int o      = oc * 64 + olocal;

    __shared__ float m_lds[B_TILE][E_DIM];         // 32 KB
    __shared__ float red[B_TILE][8][64];           // 8 KB

    // stage B_TILE mean rows: sum 16 splits, scale by 1/len
    for (int i = tx; i < B_TILE * (E_DIM / 4); i += 512) {
        const int bb = i / (E_DIM / 4);
        const int cv = i % (E_DIM / 4);
        const int b  = bc * B_TILE + bb;
        const v4f* ps = (const v4f*)(p2 + (size_t)b * S_SPLIT * E_DIM) + cv;
        v4f m = {0.f, 0.f, 0.f, 0.f};
#pragma unroll
        for (int s2 = 0; s2 < S_SPLIT; ++s2)
            m += ps[s2 * (E_DIM / 4)];
        m *= (1.0f / (float)lengths[b]);
        ((v4f*)m_lds[bb])[cv] = m;
    }
    __syncthreads();

    float acc[B_TILE] = {0.f, 0.f, 0.f, 0.f};
    const float* wp = W + (size_t)(eg * 256) * O_DIM + o;
    const float* mp = &m_lds[0][eg * 256];
#pragma unroll 4
    for (int i = 0; i < 256; ++i) {
        const float w = wp[(size_t)i * O_DIM];
#pragma unroll
        for (int bb = 0; bb < B_TILE; ++bb)
            acc[bb] += mp[bb * E_DIM + i] * w;     // LDS broadcast reads
    }
#pragma unroll
    for (int bb = 0; bb < B_TILE; ++bb)
        red[bb][eg][olocal] = acc[bb];
    __syncthreads();

    if (tx < B_TILE * 64) {
        const int bb = tx >> 6, ol = tx & 63;
        float r = bias[oc * 64 + ol];
#pragma unroll
        for (int e2 = 0; e2 < 8; ++e2) r += red[bb][e2][ol];
        out[(size_t)(bc * B_TILE + bb) * O_DIM + oc * 64 + ol] = r;
    }
}

// ---------------------------------------------------------------------------
extern "C" void kernel_launch(void* const* d_in, const int* in_sizes, int n_in,
                              void* d_out, int out_size, void* d_ws, size_t ws_size,
                              hipStream_t stream) {
    const float* x       = (const float*)d_in[0];
    const float* W       = (const float*)d_in[1];
    const float* bias    = (const float*)d_in[2];
    const int*   lengths = (const int*)d_in[3];

    const int Bn = in_sizes[3];                 // 16
    const int On = in_sizes[2];                 // 1024
    const int En = in_sizes[1] / On;            // 2048
    const int Tn = in_sizes[0] / En;            // 131072
    (void)En; (void)out_size; (void)n_in; (void)ws_size;

    const int nChunks = (Tn + RCH - 1) / RCH;   // 2048 (exactly, T % 64 == 0)

    // workspace layout
    float* mainp  = (float*)d_ws;                                // [nChunks][E]
    float* extrap = mainp + (size_t)nChunks * E_DIM;             // [Bn][E]
    float* p2     = extrap + (size_t)Bn * E_DIM;                 // [Bn][S_SPLIT][E]

    seg_partial<<<nChunks, 256, 0, stream>>>(x, lengths, Bn, Tn, mainp, extrap);

    dim3 g2(E_DIM / 1024, Bn, S_SPLIT);
    reduce_p2<<<g2, 256, 0, stream>>>(mainp, extrap, lengths, p2);

    dim3 g3(On / 64, Bn / B_TILE);
    gemm_out<<<g3, 512, 0, stream>>>(p2, W, bias, lengths, (float*)d_out);
}

// Round 6
// 201.331 us; speedup vs baseline: 1.1180x; 1.1180x over previous
//
#include <hip/hip_runtime.h>

// Problem: x[T][E] f32, W[E][O] f32, bias[O] f32, lengths[B] int32.
// out[B][O] = (segment_mean(x, lengths) @ W) + bias
// T=131072, E=2048, O=1024, B=16 (derived at launch from in_sizes).
//
// VERBATIM revert to the measured-best (201 us) round-3 kernel.
// History: R3=201us (this source) / R4=213 (global-chunk while-loop) /
// R5=225 (dual fast/slow path). Lesson: under __launch_bounds__(256,8)
// (64-VGPR cap) extra control flow in seg_partial causes register-allocation
// damage in the hot streaming loop; ILP/occupancy were never binding
// (256 KB in flight per CU vs ~10 KB needed at 24.6 GB/s/CU, 900cy latency).
//
// Structure: (1) seg_partial: compact per-segment 64-row chunks, simple
// bounded loop, unroll 4. (2) reduce_p2: 8-way-split deterministic chunk
// reduction. (3) gemm_out: folds the 8-way sum + 1/len into LDS staging,
// 64-o x 8-egroup dot, 4 independent accumulators.

#define E_DIM 2048
#define O_DIM 1024
#define R_CHUNK 64     // rows per partial-sum chunk (T/64 + B = 2064 blocks)
#define S_SPLIT 8      // phase-2 chunk-range split factor

typedef float v4f __attribute__((ext_vector_type(4)));

// ---------------------------------------------------------------------------
// Phase 1: per-chunk partial column sums, compact 1D grid.
// Chunk->segment mapping computed redundantly per thread (16 ints, L1-hot).
// ---------------------------------------------------------------------------
__global__ __launch_bounds__(256, 8) void seg_partial(const float* __restrict__ x,
                                                      const int* __restrict__ lengths,
                                                      int Bn,
                                                      float* __restrict__ partial) {
    const int g = blockIdx.x;
    int off = 0, cb = 0, r0 = 0, r1 = 0, found = 0;
    for (int i = 0; i < Bn; ++i) {
        const int l  = lengths[i];
        const int nc = (l + R_CHUNK - 1) / R_CHUNK;
        if (g < cb + nc) {
            r0 = off + (g - cb) * R_CHUNK;
            r1 = min(r0 + R_CHUNK, off + l);
            found = 1;
            break;
        }
        off += l; cb += nc;
    }
    if (!found) return;                       // beyond total chunk count

    const int tx = threadIdx.x;
    v4f a0 = {0.f, 0.f, 0.f, 0.f};
    v4f a1 = {0.f, 0.f, 0.f, 0.f};
    const v4f* p = (const v4f*)(x + (size_t)r0 * E_DIM + tx * 4);
#pragma unroll 4
    for (int r = r0; r < r1; ++r) {
        v4f v0 = __builtin_nontemporal_load(p);        // x read exactly once
        v4f v1 = __builtin_nontemporal_load(p + 256);  // +1024 floats
        a0 += v0;
        a1 += v1;
        p += E_DIM / 4;
    }
    v4f* dst = (v4f*)(partial + (size_t)g * E_DIM + tx * 4);
    dst[0]   = a0;
    dst[256] = a1;
}

// ---------------------------------------------------------------------------
// Phase 2: 8-way-split reduction of partial chunks -> p2[b][s][e].
// grid = (E/1024, B, S_SPLIT) = 256 blocks. Fixed order => deterministic.
// ---------------------------------------------------------------------------
__global__ __launch_bounds__(256) void reduce_p2(const float* __restrict__ partial,
                                                 const int* __restrict__ lengths,
                                                 int Bn,
                                                 float* __restrict__ p2) {
    const int b = blockIdx.y;
    const int s = blockIdx.z;
    int cb = 0;
    for (int i = 0; i < b; ++i) cb += (lengths[i] + R_CHUNK - 1) / R_CHUNK;
    const int nch = (lengths[b] + R_CHUNK - 1) / R_CHUNK;
    const int c0 = (nch * s) / S_SPLIT;
    const int c1 = (nch * (s + 1)) / S_SPLIT;

    const int col = blockIdx.x * 1024 + threadIdx.x * 4;
    v4f acc = {0.f, 0.f, 0.f, 0.f};
    const v4f* p = (const v4f*)(partial + (size_t)(cb + c0) * E_DIM + col);
#pragma unroll 8
    for (int c = c0; c < c1; ++c) {           // fixed order: deterministic
        acc += *p;
        p += E_DIM / 4;
    }
    *(v4f*)(p2 + ((size_t)(b * S_SPLIT + s)) * E_DIM + col) = acc;
}

// ---------------------------------------------------------------------------
// Phase 3: out[b][o] = dot(mean[b][:], W[:][o]) + bias[o]
// grid = (O/64, B) = 256 blocks; block = 512 = 64 outputs x 8 e-groups.
// Staging sums the 8 p2 rows and applies 1/len (no separate means kernel).
// 4 independent accumulators break the FMA dependency chain.
// ---------------------------------------------------------------------------
__global__ __launch_bounds__(512) void gemm_out(const float* __restrict__ p2,
                                                const float* __restrict__ W,
                                                const float* __restrict__ bias,
                                                const int* __restrict__ lengths,
                                                float* __restrict__ out) {
    const int b      = blockIdx.y;
    const int tx     = threadIdx.x;
    const int olocal = tx & 63;
    const int eg     = tx >> 6;                    // 8 e-groups of 256
    const int o      = blockIdx.x * 64 + olocal;

    __shared__ float m_lds[E_DIM];
    __shared__ float red[S_SPLIT][64];

    // stage mean row: each thread sums one float4 across the 8 splits, scales
    {
        const float inv = 1.0f / (float)lengths[b];
        const int col = tx * 4;                    // 512 threads x 4 = 2048
        const v4f* ps = (const v4f*)(p2 + (size_t)b * S_SPLIT * E_DIM + col);
        v4f m = {0.f, 0.f, 0.f, 0.f};
#pragma unroll
        for (int s = 0; s < S_SPLIT; ++s)
            m += ps[s * (E_DIM / 4)];
        m *= inv;
        *(v4f*)(m_lds + col) = m;
    }
    __syncthreads();

    float a0 = 0.f, a1 = 0.f, a2 = 0.f, a3 = 0.f;
    const float* wp = W + (size_t)(eg * 256) * O_DIM + o;
    const float* mp = m_lds + eg * 256;
#pragma unroll 8
    for (int i = 0; i < 256; i += 4) {
        a0 += mp[i + 0] * wp[(size_t)(i + 0) * O_DIM];
        a1 += mp[i + 1] * wp[(size_t)(i + 1) * O_DIM];
        a2 += mp[i + 2] * wp[(size_t)(i + 2) * O_DIM];
        a3 += mp[i + 3] * wp[(size_t)(i + 3) * O_DIM];
    }
    red[eg][olocal] = (a0 + a1) + (a2 + a3);
    __syncthreads();

    if (tx < 64) {
        float r = bias[blockIdx.x * 64 + tx];
#pragma unroll
        for (int s = 0; s < S_SPLIT; ++s) r += red[s][tx];
        out[b * O_DIM + blockIdx.x * 64 + tx] = r;
    }
}

// ---------------------------------------------------------------------------
extern "C" void kernel_launch(void* const* d_in, const int* in_sizes, int n_in,
                              void* d_out, int out_size, void* d_ws, size_t ws_size,
                              hipStream_t stream) {
    const float* x       = (const float*)d_in[0];
    const float* W       = (const float*)d_in[1];
    const float* bias    = (const float*)d_in[2];
    const int*   lengths = (const int*)d_in[3];

    const int Bn = in_sizes[3];                 // 16
    const int On = in_sizes[2];                 // 1024
    const int En = in_sizes[1] / On;            // 2048
    const int Tn = in_sizes[0] / En;            // 131072
    (void)En; (void)out_size; (void)n_in; (void)ws_size;

    const int maxChunks      = (Tn + R_CHUNK - 1) / R_CHUNK;  // 2048
    const int maxTotalChunks = maxChunks + Bn;                // 2064

    // workspace layout
    float* partial = (float*)d_ws;                                  // [2064][E]
    float* p2      = partial + (size_t)maxTotalChunks * E_DIM;      // [B][S][E]

    seg_partial<<<maxTotalChunks, 256, 0, stream>>>(x, lengths, Bn, partial);

    dim3 g2(E_DIM / 1024, Bn, S_SPLIT);
    reduce_p2<<<g2, 256, 0, stream>>>(partial, lengths, Bn, p2);

    dim3 g3(On / 64, Bn);
    gemm_out<<<g3, 512, 0, stream>>>(p2, W, bias, lengths, (float*)d_out);
}

// Round 7
// 198.080 us; speedup vs baseline: 1.1363x; 1.0164x over previous
//
#include <hip/hip_runtime.h>

// Problem: x[T][E] f32, W[E][O] f32, bias[O] f32, lengths[B] int32.
// out[B][O] = (segment_mean(x, lengths) @ W) + bias
// T=131072, E=2048, O=1024, B=16 (derived at launch from in_sizes).
//
// Roofline: one streaming read of x (1.074 GB) => ~168 us at 6.4 TB/s.
//
// History: R3/R6 = 201 us (per-segment chunks; ~13 us straggler tail from
// 2064 blocks in 2048 concurrency slots). R4=213, R5=225: boundary logic /
// dual-path in the hot kernel wrecked codegen. Lesson: hot kernel must be
// single-path, branch-free.
//
// This version: (1) sum64 — 2048 branch-free blocks, block g sums global
// rows [64g,64g+64) -> main[g]; zero stragglers, no lengths dependency.
// (2) reduce_p2 — per (segment b, split s): sums fully-contained chunks
// from main + re-reads <=63 head and <=63 tail boundary rows from x
// (<=16 MB extra, head/chunk/tail all split across the 8 s-blocks).
// (3) gemm_out — unchanged from measured-good R6.

#define E_DIM 2048
#define O_DIM 1024
#define RCH 64        // rows per global chunk
#define S_SPLIT 8     // phase-2 split factor

typedef float v4f __attribute__((ext_vector_type(4)));

// ---------------------------------------------------------------------------
// Phase 1: branch-free global 64-row chunk sums. grid = T/64 = 2048 blocks
// = 256 CU x 8 blocks/CU exactly; every block does identical work.
// ---------------------------------------------------------------------------
__global__ __launch_bounds__(256, 8) void sum64(const float* __restrict__ x,
                                                float* __restrict__ mainp) {
    const int g  = blockIdx.x;
    const int tx = threadIdx.x;
    const v4f* p = (const v4f*)(x + (size_t)g * (RCH * E_DIM)) + tx;
    v4f a0 = {0.f, 0.f, 0.f, 0.f};
    v4f a1 = {0.f, 0.f, 0.f, 0.f};
#pragma unroll 4
    for (int r = 0; r < RCH; ++r) {
        a0 += __builtin_nontemporal_load(p);        // x read exactly once
        a1 += __builtin_nontemporal_load(p + 256);  // +1024 floats
        p += E_DIM / 4;
    }
    v4f* d = (v4f*)(mainp + (size_t)g * E_DIM) + tx;
    d[0]   = a0;
    d[256] = a1;
}

// ---------------------------------------------------------------------------
// Phase 2: segment b, split s: head boundary rows (from x) + full chunks
// (from mainp) + tail boundary rows (from x), each range split across the
// S_SPLIT s-blocks. Fixed order => deterministic. grid = (2, B, S_SPLIT).
// ---------------------------------------------------------------------------
__global__ __launch_bounds__(256) void reduce_p2(const float* __restrict__ mainp,
                                                 const float* __restrict__ x,
                                                 const int* __restrict__ lengths,
                                                 float* __restrict__ p2) {
    const int b = blockIdx.y;
    const int s = blockIdx.z;
    int start = 0;
    for (int i = 0; i < b; ++i) start += lengths[i];
    const int end = start + lengths[b];

    const int cs = (start + RCH - 1) / RCH;   // first fully-contained chunk
    const int ce = end / RCH;                  // exclusive bound of full chunks
    int headLo, headHi, tailLo, tailHi, c0, c1;
    if (ce < cs) {                             // segment within a single chunk
        headLo = start; headHi = end;
        tailLo = 0;     tailHi = 0;
        c0 = 0;         c1 = 0;
    } else {
        headLo = start;    headHi = cs * RCH;  // empty if start % 64 == 0
        tailLo = ce * RCH; tailHi = end;       // empty if end   % 64 == 0
        const int n = ce - cs;
        c0 = cs + (n * s) / S_SPLIT;
        c1 = cs + (n * (s + 1)) / S_SPLIT;
    }
    const int hn = headHi - headLo;
    const int h0 = headLo + (hn * s) / S_SPLIT;
    const int h1 = headLo + (hn * (s + 1)) / S_SPLIT;
    const int tn = tailHi - tailLo;
    const int t0 = tailLo + (tn * s) / S_SPLIT;
    const int t1 = tailLo + (tn * (s + 1)) / S_SPLIT;

    const int col = blockIdx.x * 1024 + threadIdx.x * 4;
    v4f acc = {0.f, 0.f, 0.f, 0.f};
    for (int r = h0; r < h1; ++r)                       // head rows from x
        acc += *(const v4f*)(x + (size_t)r * E_DIM + col);
    const v4f* p = (const v4f*)(mainp + (size_t)c0 * E_DIM + col);
#pragma unroll 4
    for (int c = c0; c < c1; ++c) {                     // full chunks
        acc += *p;
        p += E_DIM / 4;
    }
    for (int r = t0; r < t1; ++r)                       // tail rows from x
        acc += *(const v4f*)(x + (size_t)r * E_DIM + col);
    *(v4f*)(p2 + ((size_t)(b * S_SPLIT + s)) * E_DIM + col) = acc;
}

// ---------------------------------------------------------------------------
// Phase 3: out[b][o] = dot(mean[b][:], W[:][o]) + bias[o]
// grid = (O/64, B) = 256 blocks; block = 512 = 64 outputs x 8 e-groups.
// Staging sums the 8 p2 rows and applies 1/len.
// ---------------------------------------------------------------------------
__global__ __launch_bounds__(512) void gemm_out(const float* __restrict__ p2,
                                                const float* __restrict__ W,
                                                const float* __restrict__ bias,
                                                const int* __restrict__ lengths,
                                                float* __restrict__ out) {
    const int b      = blockIdx.y;
    const int tx     = threadIdx.x;
    const int olocal = tx & 63;
    const int eg     = tx >> 6;                    // 8 e-groups of 256
    const int o      = blockIdx.x * 64 + olocal;

    __shared__ float m_lds[E_DIM];
    __shared__ float red[S_SPLIT][64];

    // stage mean row: each thread sums one float4 across the 8 splits, scales
    {
        const float inv = 1.0f / (float)lengths[b];
        const int col = tx * 4;                    // 512 threads x 4 = 2048
        const v4f* ps = (const v4f*)(p2 + (size_t)b * S_SPLIT * E_DIM + col);
        v4f m = {0.f, 0.f, 0.f, 0.f};
#pragma unroll
        for (int s = 0; s < S_SPLIT; ++s)
            m += ps[s * (E_DIM / 4)];
        m *= inv;
        *(v4f*)(m_lds + col) = m;
    }
    __syncthreads();

    float a0 = 0.f, a1 = 0.f, a2 = 0.f, a3 = 0.f;
    const float* wp = W + (size_t)(eg * 256) * O_DIM + o;
    const float* mp = m_lds + eg * 256;
#pragma unroll 8
    for (int i = 0; i < 256; i += 4) {
        a0 += mp[i + 0] * wp[(size_t)(i + 0) * O_DIM];
        a1 += mp[i + 1] * wp[(size_t)(i + 1) * O_DIM];
        a2 += mp[i + 2] * wp[(size_t)(i + 2) * O_DIM];
        a3 += mp[i + 3] * wp[(size_t)(i + 3) * O_DIM];
    }
    red[eg][olocal] = (a0 + a1) + (a2 + a3);
    __syncthreads();

    if (tx < 64) {
        float r = bias[blockIdx.x * 64 + tx];
#pragma unroll
        for (int s = 0; s < S_SPLIT; ++s) r += red[s][tx];
        out[b * O_DIM + blockIdx.x * 64 + tx] = r;
    }
}

// ---------------------------------------------------------------------------
extern "C" void kernel_launch(void* const* d_in, const int* in_sizes, int n_in,
                              void* d_out, int out_size, void* d_ws, size_t ws_size,
                              hipStream_t stream) {
    const float* x       = (const float*)d_in[0];
    const float* W       = (const float*)d_in[1];
    const float* bias    = (const float*)d_in[2];
    const int*   lengths = (const int*)d_in[3];

    const int Bn = in_sizes[3];                 // 16
    const int On = in_sizes[2];                 // 1024
    const int En = in_sizes[1] / On;            // 2048
    const int Tn = in_sizes[0] / En;            // 131072
    (void)En; (void)out_size; (void)n_in; (void)ws_size;

    const int nChunks = Tn / RCH;               // 2048 (T % 64 == 0)

    // workspace layout
    float* mainp = (float*)d_ws;                                 // [2048][E]
    float* p2    = mainp + (size_t)nChunks * E_DIM;              // [B][S][E]

    sum64<<<nChunks, 256, 0, stream>>>(x, mainp);

    dim3 g2(E_DIM / 1024, Bn, S_SPLIT);
    reduce_p2<<<g2, 256, 0, stream>>>(mainp, x, lengths, p2);

    dim3 g3(On / 64, Bn);
    gemm_out<<<g3, 512, 0, stream>>>(p2, W, bias, lengths, (float*)d_out);
}